// Round 1
// 1275.545 us; speedup vs baseline: 1.1073x; 1.1073x over previous
//
#include <hip/hip_runtime.h>

#define B_   2048   // batch
#define H_   512    // hidden
#define I_   128    // input size
#define G4   2048   // 4*H
#define SEQ  100
#define DEC  29
#define OUT_ 128
#define TEAM 16     // blocks per row-slab team

typedef __attribute__((ext_vector_type(8))) short bf16x8;
typedef __attribute__((ext_vector_type(4))) float f32x4;
typedef __attribute__((address_space(3))) unsigned int       lds_u32;
typedef __attribute__((address_space(1))) const unsigned int glb_u32c;

__device__ inline unsigned short f2bf(float f) {
    union { float f; unsigned int u; } v; v.f = f;
    unsigned int u = v.u + 0x7fffu + ((v.u >> 16) & 1u);
    return (unsigned short)(u >> 16);
}
__device__ inline float sigm(float x)  { return 1.f / (1.f + __expf(-x)); }
__device__ inline float tanh_(float x) { return 2.f / (1.f + __expf(-2.f * x)) - 1.f; }

// aux: 0 = normal (L1/L2 cached); 17 = SC0|SC1 coherent bypass (read from L3
// coherence point — required for cross-XCD-produced data, leaves L2 intact).
template <int AUX>
__device__ inline void gl16(const unsigned short* g, unsigned short* l) {
    __builtin_amdgcn_global_load_lds((glb_u32c*)g, (lds_u32*)l, 16, 0, AUX);
}

#define WAIT_VM(n) asm volatile("s_waitcnt vmcnt(" #n ")" ::: "memory")

template <int N> struct ic { static constexpr int v = N; };

// Persistent encoder+decoder+projection kernel.
// Grid 256 blocks x 512 thr (1 block/CU). Block tile: 128 batch rows x
// 128 gate-cols (= 32 h-cols x 4 gates). rg = blockIdx&15 (row team),
// cgB = blockIdx>>4 (col group).
//
// v3 structure (this round): weights live in REGISTERS (per-wave 64r x 32c
// tile, gate-interleaved cols: each wave holds all 4 gates for its 8 h-cols
// -> epilogue is wave-local + one shfl_xor(8) exchange). LDS stages the
// A (h/x) tile only: 4 x 16KB chunk buffers, 3-deep prefetch with COUNTED
// s_waitcnt vmcnt(N) + raw s_barrier (no per-chunk vmcnt(0) drain).
// Team sync + sc1 write-through h exchange unchanged from verified v2.
__global__ __launch_bounds__(512, 2) void persist(
    const unsigned short* __restrict__ h0b,   // [B_,H_] bf16 initial h
    const unsigned short* __restrict__ xbf,   // [SEQ,B_,I_] bf16 inputs
    const unsigned short* __restrict__ Wce,   // [G4,640] enc weights (Whh|Wih)
    const unsigned short* __restrict__ Wd,    // [G4,512] dec combined weights
    const unsigned short* __restrict__ Wl,    // [OUT_,512] output proj
    const float* __restrict__ be, const float* __restrict__ bd,
    const float* __restrict__ blin,
    const float* __restrict__ c_enc0, const float* __restrict__ c_dec0,
    unsigned short* __restrict__ hp0, unsigned short* __restrict__ hp1,
    unsigned short* __restrict__ hs,          // [30,B_,H_] bf16
    float* __restrict__ out_y,                // [30,B_,OUT_]
    float* __restrict__ out_hEnc, float* __restrict__ out_cEnc,
    float* __restrict__ out_hDec, float* __restrict__ out_cDec,
    unsigned int* __restrict__ bar)           // [16][64] uints (cnt @0, gen @32)
{
    __shared__ unsigned short smem[32768];    // 64 KB = 4 x 16KB A-chunk bufs

    const int tid  = threadIdx.x;
    const int b    = blockIdx.x;
    const int rg   = b & 15;                  // row-slab / team id
    const int cgB  = b >> 4;                  // col-group 0..15
    const int m0   = rg * 128;
    const int c0   = cgB * 32;

    const int lane = tid & 63, w = tid >> 6;
    const int quad = lane >> 4, l16 = lane & 15;
    const int bit3 = (lane >> 3) & 1;         // gate-pair select within frag
    const int co   = lane & 7;                // h-col offset within wave
    const int wc   = w & 3;                   // wave col-group 0..3
    const int rbase = (w >> 2) * 64;          // wave row base 0/64
    const int jlo  = bit3 * 2;                // owned j rows after exchange

    const int hcl  = wc * 8 + co;             // local h col 0..31
    const int hcol = c0 + hcl;                // global h col

    unsigned int* bcnt = bar + rg * 64;
    unsigned int* bgen = bcnt + 32;           // 128 B away: separate line
    unsigned int  my_gen = 0;

    // ---- A staging geometry (same XOR swizzle as verified v2) ----
    const int srow8 = lane >> 3;              // 0..7: row within 8-row group
    const int segl  = co ^ srow8;             // pre-swizzled source segment

    // reader LDS byte offsets (row*128 + swizzled seg*16), per ks
    int lds_off[2];
#pragma unroll
    for (int ks = 0; ks < 2; ++ks)
        lds_off[ks] = (rbase + l16) * 128 + (((ks * 4 + quad) ^ (lane & 7)) * 16);

    bf16x8 Bw[2][20];                         // weights in regs: 2 cf x 20 ks
    f32x4  acc[4][2];                         // 4 row-frags x 2 col-frags
    float  c_reg[4][2];                       // cell state for owned (rf, jj)

    // Load this wave's B fragments straight from global in MFMA layout:
    // frag col c = l16 -> gate = cf*2 + bit3, h-col = cb + hcl; k = ksg*32+quad*8.
    auto loadB = [&](const unsigned short* W, int Kw, int GS, int cb, int nks) {
#pragma unroll
        for (int cf = 0; cf < 2; ++cf) {
            const int grow = (cf * 2 + bit3) * GS + cb + hcl;
            const unsigned short* wp = W + (size_t)grow * Kw + quad * 8;
#pragma unroll
            for (int ksg = 0; ksg < 20; ++ksg)
                if (ksg < nks)
                    Bw[cf][ksg] = *(const bf16x8*)(wp + ksg * 32);
        }
    };

    // Full K-loop GEMM: A from LDS (3-deep counted-vmcnt pipeline), B from regs.
    auto gemm = [&](auto kcn_t, auto xt_t,
                    const unsigned short* Asrc, const unsigned short* xsrc) {
        constexpr int KCN = decltype(kcn_t)::v;
        constexpr int XT  = decltype(xt_t)::v;

        auto stg = [&](int kc, int buf, bool isx) {
            unsigned short* dstl = smem + buf * 8192 + w * 1024;  // 16 rows
            if (isx) {            // encoder x-chunks (k 512..639): cached
                const unsigned short* g0 =
                    xsrc + (m0 + w * 16 + srow8) * I_ + (kc - 8) * 64 + segl * 8;
                gl16<0>(g0, dstl);
                gl16<0>(g0 + 8 * I_, dstl + 512);
            } else {              // h slabs: sc1-bypass coherent reads
                const unsigned short* g0 =
                    Asrc + (m0 + w * 16 + srow8) * H_ + kc * 64 + segl * 8;
                gl16<17>(g0, dstl);
                gl16<17>(g0 + 8 * H_, dstl + 512);
            }
        };

#pragma unroll
        for (int rf = 0; rf < 4; ++rf)
#pragma unroll
            for (int cf = 0; cf < 2; ++cf) acc[rf][cf] = (f32x4){0.f, 0.f, 0.f, 0.f};

        __syncthreads();          // all waves done with previous phase's smem
        stg(0, 0, false);
        stg(1, 1, false);
        stg(2, 2, false);
#pragma unroll
        for (int kc = 0; kc < KCN; ++kc) {
            // counted wait: chunk kc landed, chunks kc+1/kc+2 stay in flight
            if (kc < KCN - 2)      { WAIT_VM(4); }
            else if (kc == KCN - 2){ WAIT_VM(2); }
            else                   { WAIT_VM(0); }
            __builtin_amdgcn_s_barrier();
            __builtin_amdgcn_sched_barrier(0);   // pin: no reads hoist, no stale sink
            if (kc + 3 < KCN) stg(kc + 3, (kc + 3) & 3, XT && (kc + 3) >= 8);

            const char* sb = (const char*)smem + ((kc & 3) * 16384);
            __builtin_amdgcn_s_setprio(1);
#pragma unroll
            for (int ks = 0; ks < 2; ++ks) {
                const int kk = kc * 2 + ks;
                const bf16x8 a0 = *(const bf16x8*)(sb + lds_off[ks]);
                const bf16x8 a1 = *(const bf16x8*)(sb + lds_off[ks] + 2048);
                const bf16x8 a2 = *(const bf16x8*)(sb + lds_off[ks] + 4096);
                const bf16x8 a3 = *(const bf16x8*)(sb + lds_off[ks] + 6144);
                acc[0][0] = __builtin_amdgcn_mfma_f32_16x16x32_bf16(a0, Bw[0][kk], acc[0][0], 0, 0, 0);
                acc[1][0] = __builtin_amdgcn_mfma_f32_16x16x32_bf16(a1, Bw[0][kk], acc[1][0], 0, 0, 0);
                acc[2][0] = __builtin_amdgcn_mfma_f32_16x16x32_bf16(a2, Bw[0][kk], acc[2][0], 0, 0, 0);
                acc[3][0] = __builtin_amdgcn_mfma_f32_16x16x32_bf16(a3, Bw[0][kk], acc[3][0], 0, 0, 0);
                acc[0][1] = __builtin_amdgcn_mfma_f32_16x16x32_bf16(a0, Bw[1][kk], acc[0][1], 0, 0, 0);
                acc[1][1] = __builtin_amdgcn_mfma_f32_16x16x32_bf16(a1, Bw[1][kk], acc[1][1], 0, 0, 0);
                acc[2][1] = __builtin_amdgcn_mfma_f32_16x16x32_bf16(a2, Bw[1][kk], acc[2][1], 0, 0, 0);
                acc[3][1] = __builtin_amdgcn_mfma_f32_16x16x32_bf16(a3, Bw[1][kk], acc[3][1], 0, 0, 0);
            }
            __builtin_amdgcn_s_setprio(0);
        }
    };

    // Monotonic counting barrier (no reset => no reset/gen reorder race).
    // No fences: h data was written through (sc1) and drained (vmcnt0 before
    // s_barrier), so the relaxed RMW at the coherence point is ordered after it.
    auto team_barrier = [&]() {
        __syncthreads();
        if (tid == 0) {
            unsigned old = __hip_atomic_fetch_add(bcnt, 1u, __ATOMIC_RELAXED,
                                                  __HIP_MEMORY_SCOPE_AGENT);
            if (old == (my_gen + 1u) * TEAM - 1u) {
                __hip_atomic_fetch_add(bgen, 1u, __ATOMIC_RELAXED,
                                       __HIP_MEMORY_SCOPE_AGENT);
            } else {
                while (__hip_atomic_load(bgen, __ATOMIC_RELAXED,
                                         __HIP_MEMORY_SCOPE_AGENT) <= my_gen)
                    __builtin_amdgcn_s_sleep(2);
            }
        }
        my_gen++;
        __syncthreads();
    };

    // LSTM cell epilogue. Gate layout per wave: frag col c = l16 ->
    // gate = cf*2 + bit3, h-col = hcl. Lanes l and l^8 hold (i,g)/(f,o) for
    // the same h-col; exchange via shfl_xor(8), split row-j by bit3.
    auto cell_epi = [&](float bi, float bf_, float bg, float bo,
                        unsigned short* dst, float* hdump, float* cdump) {
        unsigned short* hstage = smem;   // reuse buf0 region (post-gemm safe)
#pragma unroll
        for (int rf = 0; rf < 4; ++rf) {
#pragma unroll
            for (int jj = 0; jj < 2; ++jj) {
                const float a0lo = acc[rf][0][jj],     a0hi = acc[rf][0][2 + jj];
                const float a1lo = acc[rf][1][jj],     a1hi = acc[rf][1][2 + jj];
                const float p0lo = __shfl_xor(a0lo, 8), p0hi = __shfl_xor(a0hi, 8);
                const float p1lo = __shfl_xor(a1lo, 8), p1hi = __shfl_xor(a1hi, 8);
                const float own0 = bit3 ? a0hi : a0lo;   // own  cf0 @ owned j
                const float own1 = bit3 ? a1hi : a1lo;   // own  cf1 @ owned j
                const float par0 = bit3 ? p0hi : p0lo;   // peer cf0 @ owned j
                const float par1 = bit3 ? p1hi : p1lo;   // peer cf1 @ owned j
                const float gi = (bit3 ? par0 : own0) + bi;
                const float gf = (bit3 ? own0 : par0) + bf_;
                const float gg = (bit3 ? par1 : own1) + bg;
                const float go = (bit3 ? own1 : par1) + bo;
                const float ii = sigm(gi), ff = sigm(gf);
                const float g2 = tanh_(gg), oo = sigm(go);
                const float cn = ff * c_reg[rf][jj] + ii * g2;
                c_reg[rf][jj] = cn;
                const float hn = oo * tanh_(cn);
                const int row_l = rbase + rf * 16 + quad * 4 + jlo + jj;
                hstage[row_l * 32 + hcl] = f2bf(hn);
                if (hdump) {
                    const size_t idx = (size_t)(m0 + row_l) * H_ + hcol;
                    hdump[idx] = hn; cdump[idx] = cn;
                }
            }
        }
        __syncthreads();
        const unsigned int* h32 = (const unsigned int*)smem;
#pragma unroll
        for (int i = 0; i < 4; ++i) {
            const int idx = tid + i * 512;          // 0..2047
            const int row = idx >> 4, cp = idx & 15;
            unsigned int* gp =
                (unsigned int*)(dst + (size_t)(m0 + row) * H_ + c0) + cp;
            __hip_atomic_store(gp, h32[idx], __ATOMIC_RELAXED,
                               __HIP_MEMORY_SCOPE_AGENT);
        }
    };

    // ================= encoder: 100 steps =================
    {
        loadB(Wce, 640, H_, c0, 20);
        const float bi = be[hcol],            bf_ = be[H_ + hcol],
                    bg = be[2 * H_ + hcol],   bo  = be[3 * H_ + hcol];
#pragma unroll
        for (int rf = 0; rf < 4; ++rf)
#pragma unroll
            for (int jj = 0; jj < 2; ++jj) {
                const int row_l = rbase + rf * 16 + quad * 4 + jlo + jj;
                c_reg[rf][jj] = c_enc0[(size_t)(m0 + row_l) * H_ + hcol];
            }
        for (int t = 0; t < SEQ; ++t) {
            const unsigned short* src = (t == 0) ? h0b : ((t & 1) ? hp0 : hp1);
            unsigned short*       dst = (t == SEQ - 1) ? hs : ((t & 1) ? hp1 : hp0);
            const bool last = (t == SEQ - 1);
            gemm(ic<10>{}, ic<1>{}, src, xbf + (size_t)t * B_ * I_);
            cell_epi(bi, bf_, bg, bo, dst,
                     last ? out_hEnc : nullptr, last ? out_cEnc : nullptr);
            team_barrier();
        }
    }

    // ================= decoder: 29 steps =================
    {
        loadB(Wd, 512, H_, c0, 16);
        const float bi = bd[hcol],            bf_ = bd[H_ + hcol],
                    bg = bd[2 * H_ + hcol],   bo  = bd[3 * H_ + hcol];
#pragma unroll
        for (int rf = 0; rf < 4; ++rf)
#pragma unroll
            for (int jj = 0; jj < 2; ++jj) {
                const int row_l = rbase + rf * 16 + quad * 4 + jlo + jj;
                c_reg[rf][jj] = c_dec0[(size_t)(m0 + row_l) * H_ + hcol];
            }
        for (int s = 0; s < DEC; ++s) {
            const bool last = (s == DEC - 1);
            gemm(ic<8>{}, ic<0>{}, hs + (size_t)s * B_ * H_, nullptr);
            cell_epi(bi, bf_, bg, bo, hs + (size_t)(s + 1) * B_ * H_,
                     last ? out_hDec : nullptr, last ? out_cDec : nullptr);
            team_barrier();
        }
    }

    // ===== output projection: y[s] = hs[s] @ Wl^T + blin (team-local rows) ===
    {
        loadB(Wl, 512, 32, 0, 16);   // out-col = (cf*2+bit3)*32 + hcl
        for (int s = cgB; s < DEC + 1; s += 16) {
            gemm(ic<8>{}, ic<0>{}, hs + (size_t)s * B_ * H_, nullptr);
#pragma unroll
            for (int cf = 0; cf < 2; ++cf) {
                const int oc = (cf * 2 + bit3) * 32 + hcl;
                const float bbv = blin[oc];
#pragma unroll
                for (int rf = 0; rf < 4; ++rf)
#pragma unroll
                    for (int j = 0; j < 4; ++j) {
                        const int row = m0 + rbase + rf * 16 + quad * 4 + j;
                        out_y[(size_t)s * B_ * OUT_ + (size_t)row * OUT_ + oc] =
                            acc[rf][cf][j] + bbv;
                    }
            }
        }
    }
}

// Weight prep: Wce[r][k] = k<512 ? Whh_e[r][k] : Wih_e[r][k-512];
// Wd = bf16(Wih_d + Whh_d); Wl = bf16(W_lin); biases combined.
__global__ void prep(const float* __restrict__ whh_e, const float* __restrict__ wih_e,
                     const float* __restrict__ wih_d, const float* __restrict__ whh_d,
                     const float* __restrict__ wlin,
                     const float* __restrict__ bie, const float* __restrict__ bhe,
                     const float* __restrict__ bid, const float* __restrict__ bhd,
                     unsigned short* __restrict__ Wce, unsigned short* __restrict__ Wd,
                     unsigned short* __restrict__ Wl,
                     float* __restrict__ be, float* __restrict__ bd)
{
    const int i = blockIdx.x * blockDim.x + threadIdx.x;
    if (i < G4 * 640) {
        const int r = i / 640, k = i % 640;
        Wce[i] = f2bf(k < H_ ? whh_e[r * H_ + k] : wih_e[r * I_ + (k - H_)]);
    }
    if (i < G4 * H_)   Wd[i] = f2bf(wih_d[i] + whh_d[i]);
    if (i < OUT_ * H_) Wl[i] = f2bf(wlin[i]);
    if (i < G4) { be[i] = bie[i] + bhe[i]; bd[i] = bid[i] + bhd[i]; }
}

__global__ void xconv(const float* __restrict__ x, unsigned short* __restrict__ xb, int n4)
{
    const int i = blockIdx.x * blockDim.x + threadIdx.x;
    if (i < n4) {
        const float4 f = *(const float4*)(x + (size_t)i * 4);
        ushort4 o;
        o.x = f2bf(f.x); o.y = f2bf(f.y); o.z = f2bf(f.z); o.w = f2bf(f.w);
        *(ushort4*)(xb + (size_t)i * 4) = o;
    }
}

__global__ void inith(const float* __restrict__ h0, unsigned short* __restrict__ hb)
{
    const int i = blockIdx.x * blockDim.x + threadIdx.x;
    if (i < B_ * H_) hb[i] = f2bf(h0[i]);
}

extern "C" void kernel_launch(void* const* d_in, const int* in_sizes, int n_in,
                              void* d_out, int out_size, void* d_ws, size_t ws_size,
                              hipStream_t stream) {
    (void)in_sizes; (void)n_in; (void)out_size; (void)ws_size;
    const float* input  = (const float*)d_in[0];
    const float* h_enc0 = (const float*)d_in[1];
    // d_in[2] hidden_decoder is unused by the reference
    const float* c_enc0 = (const float*)d_in[3];
    const float* c_dec0 = (const float*)d_in[4];
    const float* Wih_e  = (const float*)d_in[5];
    const float* Whh_e  = (const float*)d_in[6];
    const float* bih_e  = (const float*)d_in[7];
    const float* bhh_e  = (const float*)d_in[8];
    const float* Wih_d  = (const float*)d_in[9];
    const float* Whh_d  = (const float*)d_in[10];
    const float* bih_d  = (const float*)d_in[11];
    const float* bhh_d  = (const float*)d_in[12];
    const float* Wlin   = (const float*)d_in[13];
    const float* blin   = (const float*)d_in[14];
    float* out = (float*)d_out;

    char* ws = (char*)d_ws;
    size_t off = 0;
    auto alloc = [&](size_t bytes) -> void* {
        void* p = ws + off;
        off = (off + bytes + 255) & ~(size_t)255;
        return p;
    };
    unsigned short* Wce = (unsigned short*)alloc((size_t)G4 * 640 * 2);
    unsigned short* Wd  = (unsigned short*)alloc((size_t)G4 * H_ * 2);
    unsigned short* Wl  = (unsigned short*)alloc((size_t)OUT_ * H_ * 2);
    float* be = (float*)alloc((size_t)G4 * 4);
    float* bd = (float*)alloc((size_t)G4 * 4);
    unsigned short* h0b = (unsigned short*)alloc((size_t)B_ * H_ * 2);
    unsigned short* hp0 = (unsigned short*)alloc((size_t)B_ * H_ * 2);
    unsigned short* hp1 = (unsigned short*)alloc((size_t)B_ * H_ * 2);
    unsigned short* xbf = (unsigned short*)alloc((size_t)SEQ * B_ * I_ * 2);
    unsigned short* hs  = (unsigned short*)alloc((size_t)(DEC + 1) * B_ * H_ * 2);
    unsigned int*   bar = (unsigned int*)alloc(16 * 64 * 4);

    float* out_y    = out;                                   // [30, B_, OUT_]
    float* out_hEnc = out + (size_t)(DEC + 1) * B_ * OUT_;
    float* out_hDec = out_hEnc + (size_t)B_ * H_;
    float* out_cEnc = out_hDec + (size_t)B_ * H_;
    float* out_cDec = out_cEnc + (size_t)B_ * H_;

    prep<<<(G4 * 640 + 255) / 256, 256, 0, stream>>>(
        Whh_e, Wih_e, Wih_d, Whh_d, Wlin, bih_e, bhh_e, bih_d, bhh_d,
        Wce, Wd, Wl, be, bd);
    xconv<<<(SEQ * B_ * I_ / 4 + 255) / 256, 256, 0, stream>>>(input, xbf, SEQ * B_ * I_ / 4);
    inith<<<(B_ * H_ + 255) / 256, 256, 0, stream>>>(h_enc0, h0b);
    hipMemsetAsync(bar, 0, 16 * 64 * 4, stream);

    persist<<<256, 512, 0, stream>>>(
        h0b, xbf, Wce, Wd, Wl, be, bd, blin, c_enc0, c_dec0,
        hp0, hp1, hs, out_y, out_hEnc, out_cEnc, out_hDec, out_cDec, bar);
}